// Round 5
// baseline (211.605 us; speedup 1.0000x reference)
//
#include <hip/hip_runtime.h>

#define NB 16
#define T 16000
#define NF 64
#define TILE 252              // output timesteps per block
#define TT 256                // threads per block
#define HALO 32
#define ROWS (TILE + HALO)    // 284
#define RSU 18                // per-pass row stride in dwords: L dw 0..7, R dw 8..15, pad 2
#define N_ITD 16
#define N_ILD 8
#define NUNITS (ROWS * 4)     // 1136 8-float staging units per pass
#define NSTG ((NUNITS + TT - 1) / TT)   // 5 (last partial)

typedef _Float16 half2_t __attribute__((ext_vector_type(2)));

__device__ __forceinline__ unsigned int pk2h(float a, float b) {
    half2_t h;
    h.x = (_Float16)a;
    h.y = (_Float16)b;
    return __builtin_bit_cast(unsigned int, h);
}
__device__ __forceinline__ float dot2(unsigned int a, unsigned int b, float c) {
    return __builtin_amdgcn_fdot2(__builtin_bit_cast(half2_t, a),
                                  __builtin_bit_cast(half2_t, b), c, false);
}

// LDS = 2 * 284*18*4 = 40896 B -> 4 blocks/CU.
// 4-pass (16ch each) double-buffered pipeline: loads for pass p in flight
// while pass p-1 computes from the other buffer (T14 async-stage split).
__global__ __launch_bounds__(TT, 4) void biaural_kernel(const float* __restrict__ L,
                                                        const float* __restrict__ R,
                                                        float* __restrict__ out) {
    __shared__ unsigned int sh[2][ROWS * RSU];

    const int b = blockIdx.y;
    const int t0 = blockIdx.x * TILE;
    const int tid = threadIdx.x;

    const float* __restrict__ Lb = L + (size_t)b * T * NF;
    const float* __restrict__ Rb = R + (size_t)b * T * NF;

    // staging geometry: unit n = (row = n>>2, q = n&3); q is tid&3 (loop-invariant).
    // q 0,1 -> left ear 8-float chunk; q 2,3 -> right ear chunk.
    const int q = tid & 3;
    const float* __restrict__ eb = (q < 2) ? Lb : Rb;
    const int cf0 = (q & 1) * 8;

    float4 rg[NSTG][2];
    unsigned int vmask[NSTG];

    float acc[N_ITD];
#pragma unroll
    for (int i = 0; i < N_ITD; ++i) acc[i] = 0.f;
    float sumL = 0.f, sumR = 0.f;

    const int OFF[8] = {2, 6, 11, 15, 19, 23, 28, 32};
    const unsigned int ONE2 = 0x3C003C00u;   // (1.0h, 1.0h)
    const int ct = (tid < TILE) ? tid : (TILE - 1);
    const int cb = (HALO + ct) * RSU;

    auto stage_issue = [&](int p) {
#pragma unroll
        for (int it = 0; it < NSTG; ++it) {
            const int n = tid + it * TT;
            if (n < NUNITS) {
                const int row = n >> 2;
                const int gt = t0 - HALO + row;
                const int gtc = (gt < 0) ? 0 : ((gt >= T) ? (T - 1) : gt);
                vmask[it] = (gt >= 0 && gt < T) ? 0xFFFFFFFFu : 0u;
                const float* sp = eb + (size_t)gtc * NF + p * 16 + cf0;
                rg[it][0] = *(const float4*)sp;
                rg[it][1] = *(const float4*)(sp + 4);
            }
        }
    };
    auto stage_write = [&](int bi) {
#pragma unroll
        for (int it = 0; it < NSTG; ++it) {
            const int n = tid + it * TT;
            if (n < NUNITS) {
                const int row = n >> 2;
                const unsigned int vm = vmask[it];
                uint4 pk;
                pk.x = pk2h(rg[it][0].x, rg[it][0].y) & vm;
                pk.y = pk2h(rg[it][0].z, rg[it][0].w) & vm;
                pk.z = pk2h(rg[it][1].x, rg[it][1].y) & vm;
                pk.w = pk2h(rg[it][1].z, rg[it][1].w) & vm;
                *(uint4*)&sh[bi][row * RSU + q * 4] = pk;
            }
        }
    };
    auto compute = [&](int bi) {
        const unsigned int* s = sh[bi];
        const uint4 lcA = *(const uint4*)&s[cb + 0];
        const uint4 lcB = *(const uint4*)&s[cb + 4];
        const uint4 rcA = *(const uint4*)&s[cb + 8];
        const uint4 rcB = *(const uint4*)&s[cb + 12];
        sumL = dot2(lcA.x, ONE2, sumL); sumL = dot2(lcA.y, ONE2, sumL);
        sumL = dot2(lcA.z, ONE2, sumL); sumL = dot2(lcA.w, ONE2, sumL);
        sumL = dot2(lcB.x, ONE2, sumL); sumL = dot2(lcB.y, ONE2, sumL);
        sumL = dot2(lcB.z, ONE2, sumL); sumL = dot2(lcB.w, ONE2, sumL);
        sumR = dot2(rcA.x, ONE2, sumR); sumR = dot2(rcA.y, ONE2, sumR);
        sumR = dot2(rcA.z, ONE2, sumR); sumR = dot2(rcA.w, ONE2, sumR);
        sumR = dot2(rcB.x, ONE2, sumR); sumR = dot2(rcB.y, ONE2, sumR);
        sumR = dot2(rcB.z, ONE2, sumR); sumR = dot2(rcB.w, ONE2, sumR);
#pragma unroll
        for (int k = 0; k < 8; ++k) {
            const int rb = cb - OFF[k] * RSU;
            const uint4 laA = *(const uint4*)&s[rb + 0];
            const uint4 laB = *(const uint4*)&s[rb + 4];
            acc[8 + k] = dot2(laA.x, rcA.x, acc[8 + k]);
            acc[8 + k] = dot2(laA.y, rcA.y, acc[8 + k]);
            acc[8 + k] = dot2(laA.z, rcA.z, acc[8 + k]);
            acc[8 + k] = dot2(laA.w, rcA.w, acc[8 + k]);
            acc[8 + k] = dot2(laB.x, rcB.x, acc[8 + k]);
            acc[8 + k] = dot2(laB.y, rcB.y, acc[8 + k]);
            acc[8 + k] = dot2(laB.z, rcB.z, acc[8 + k]);
            acc[8 + k] = dot2(laB.w, rcB.w, acc[8 + k]);
            const uint4 raA = *(const uint4*)&s[rb + 8];
            const uint4 raB = *(const uint4*)&s[rb + 12];
            acc[7 - k] = dot2(lcA.x, raA.x, acc[7 - k]);
            acc[7 - k] = dot2(lcA.y, raA.y, acc[7 - k]);
            acc[7 - k] = dot2(lcA.z, raA.z, acc[7 - k]);
            acc[7 - k] = dot2(lcA.w, raA.w, acc[7 - k]);
            acc[7 - k] = dot2(lcB.x, raB.x, acc[7 - k]);
            acc[7 - k] = dot2(lcB.y, raB.y, acc[7 - k]);
            acc[7 - k] = dot2(lcB.z, raB.z, acc[7 - k]);
            acc[7 - k] = dot2(lcB.w, raB.w, acc[7 - k]);
        }
    };

    // ---- pipeline: stage0 -> [issue p | compute p-1 | write p] x3 -> compute 3
    stage_issue(0);
    stage_write(0);
    __syncthreads();
#pragma unroll
    for (int p = 1; p < 4; ++p) {
        stage_issue(p);           // loads in flight...
        compute((p - 1) & 1);     // ...hidden under previous pass's compute
        stage_write(p & 1);       // waits land here; writes the OTHER buffer
        __syncthreads();
    }
    compute(1);

    const int t = t0 + tid;
    if (tid < TILE && t < T) {
        // ---- ITD: [B,T,16]
        float* oitd = out + ((size_t)b * T + t) * N_ITD;
#pragma unroll
        for (int qq = 0; qq < 4; ++qq) {
            *(float4*)(oitd + qq * 4) =
                make_float4(acc[qq * 4 + 0], acc[qq * 4 + 1], acc[qq * 4 + 2], acc[qq * 4 + 3]);
        }

        // ---- ILD: [B,T,8] after the ITD block
        const float ild = (sumL - sumR) / (sumL + sumR + 1e-6f);
        const float PREFS[8] = {-1.f, -0.71428573f, -0.42857143f, -0.14285714f,
                                0.14285715f, 0.42857143f, 0.71428573f, 1.f};
        float ov[8];
#pragma unroll
        for (int j = 0; j < 8; ++j) {
            const float z = (ild - PREFS[j]) * (1.0f / 0.3f);
            ov[j] = __expf(-0.5f * z * z);
        }
        float* oild = out + (size_t)NB * T * N_ITD + ((size_t)b * T + t) * N_ILD;
        *(float4*)(oild + 0) = make_float4(ov[0], ov[1], ov[2], ov[3]);
        *(float4*)(oild + 4) = make_float4(ov[4], ov[5], ov[6], ov[7]);
    }
}

extern "C" void kernel_launch(void* const* d_in, const int* in_sizes, int n_in,
                              void* d_out, int out_size, void* d_ws, size_t ws_size,
                              hipStream_t stream) {
    const float* L = (const float*)d_in[0];
    const float* R = (const float*)d_in[1];
    float* out = (float*)d_out;
    dim3 grid((T + TILE - 1) / TILE, NB);
    biaural_kernel<<<grid, dim3(TT), 0, stream>>>(L, R, out);
}

// Round 6
// 123.855 us; speedup vs baseline: 1.7085x; 1.7085x over previous
//
#include <hip/hip_runtime.h>

#define NB 16
#define T 16000
#define NF 64
#define TILE 128              // output timesteps per block
#define TT 128                // threads per block (2 waves)
#define HALO 32
#define ROWS (TILE + HALO)    // 160
#define RSU 36                // combined row stride in dwords: L dw 0..15, R dw 16..31, pad 4
#define N_ITD 16
#define N_ILD 8

typedef _Float16 half2_t __attribute__((ext_vector_type(2)));

__device__ __forceinline__ unsigned int pk2h(float a, float b) {
    half2_t h;
    h.x = (_Float16)a;
    h.y = (_Float16)b;
    return __builtin_bit_cast(unsigned int, h);
}
__device__ __forceinline__ float dot2(unsigned int a, unsigned int b, float c) {
    return __builtin_amdgcn_fdot2(__builtin_bit_cast(half2_t, a),
                                  __builtin_bit_cast(half2_t, b), c, false);
}

// LDS = 160*36*4 = 23040 B -> 7 blocks/CU = 14 waves/CU, 2-wave barrier convoys.
// Small independent blocks decorrelate stage/compute phases across the CU.
__global__ __launch_bounds__(TT, 4) void biaural_kernel(const float* __restrict__ L,
                                                        const float* __restrict__ R,
                                                        float* __restrict__ out) {
    __shared__ unsigned int sh[ROWS * RSU];

    const int b = blockIdx.y;
    const int t0 = blockIdx.x * TILE;
    const int tid = threadIdx.x;

    const float* __restrict__ Lb = L + (size_t)b * T * NF;
    const float* __restrict__ Rb = R + (size_t)b * T * NF;

    float acc[N_ITD];
#pragma unroll
    for (int i = 0; i < N_ITD; ++i) acc[i] = 0.f;
    float sumL = 0.f, sumR = 0.f;

    const int OFF[8] = {2, 6, 11, 15, 19, 23, 28, 32};
    const unsigned int ONE2 = 0x3C003C00u;   // (1.0h, 1.0h)
    const int crowbase = (HALO + tid) * RSU;

#pragma unroll
    for (int pass = 0; pass < 2; ++pass) {
        const int pf = pass * 32;            // float offset within the 64-ch row
        if (pass) __syncthreads();           // protect LDS reuse

        // ---- stage [t0-32, t0+TILE-1] x 32ch of both ears as f16 (b128 writes)
        // 160*4/128 = 5 exact iterations, round-3-proven simple form.
        for (int n = tid; n < ROWS * 4; n += TT) {
            const int row = n >> 2;
            const int c = n & 3;             // 8-float chunk within the 32-ch slab
            const int gt = t0 - HALO + row;
            uint4 pl = make_uint4(0u, 0u, 0u, 0u);
            uint4 pr = make_uint4(0u, 0u, 0u, 0u);
            if (gt >= 0) {                   // gt < T always true for this grid
                const float* lp = Lb + (size_t)gt * NF + pf + c * 8;
                const float* rp = Rb + (size_t)gt * NF + pf + c * 8;
                float4 a0 = *(const float4*)lp;
                float4 a1 = *(const float4*)(lp + 4);
                float4 b0 = *(const float4*)rp;
                float4 b1 = *(const float4*)(rp + 4);
                pl = make_uint4(pk2h(a0.x, a0.y), pk2h(a0.z, a0.w),
                                pk2h(a1.x, a1.y), pk2h(a1.z, a1.w));
                pr = make_uint4(pk2h(b0.x, b0.y), pk2h(b0.z, b0.w),
                                pk2h(b1.x, b1.y), pk2h(b1.z, b1.w));
            }
            const int idx = row * RSU + c * 4;
            *(uint4*)&sh[idx] = pl;
            *(uint4*)&sh[idx + 16] = pr;
        }
        __syncthreads();

        // ---- compute: 4 chunks of 8 channels
#pragma unroll
        for (int c = 0; c < 4; ++c) {
            const uint4 lc = *(const uint4*)&sh[crowbase + c * 4];
            const uint4 rc = *(const uint4*)&sh[crowbase + 16 + c * 4];
            sumL = dot2(lc.x, ONE2, sumL); sumL = dot2(lc.y, ONE2, sumL);
            sumL = dot2(lc.z, ONE2, sumL); sumL = dot2(lc.w, ONE2, sumL);
            sumR = dot2(rc.x, ONE2, sumR); sumR = dot2(rc.y, ONE2, sumR);
            sumR = dot2(rc.z, ONE2, sumR); sumR = dot2(rc.w, ONE2, sumR);
#pragma unroll
            for (int k = 0; k < 8; ++k) {
                const int rb = crowbase - OFF[k] * RSU;
                const uint4 la = *(const uint4*)&sh[rb + c * 4];
                acc[8 + k] = dot2(la.x, rc.x, acc[8 + k]);
                acc[8 + k] = dot2(la.y, rc.y, acc[8 + k]);
                acc[8 + k] = dot2(la.z, rc.z, acc[8 + k]);
                acc[8 + k] = dot2(la.w, rc.w, acc[8 + k]);
                const uint4 ra = *(const uint4*)&sh[rb + 16 + c * 4];
                acc[7 - k] = dot2(lc.x, ra.x, acc[7 - k]);
                acc[7 - k] = dot2(lc.y, ra.y, acc[7 - k]);
                acc[7 - k] = dot2(lc.z, ra.z, acc[7 - k]);
                acc[7 - k] = dot2(lc.w, ra.w, acc[7 - k]);
            }
        }
    }

    const int t = t0 + tid;   // always < T (125*128 == 16000)
    // ---- ITD: [B,T,16]
    float* oitd = out + ((size_t)b * T + t) * N_ITD;
#pragma unroll
    for (int q = 0; q < 4; ++q) {
        *(float4*)(oitd + q * 4) =
            make_float4(acc[q * 4 + 0], acc[q * 4 + 1], acc[q * 4 + 2], acc[q * 4 + 3]);
    }

    // ---- ILD: [B,T,8] after the ITD block
    const float ild = (sumL - sumR) / (sumL + sumR + 1e-6f);
    const float PREFS[8] = {-1.f, -0.71428573f, -0.42857143f, -0.14285714f,
                            0.14285715f, 0.42857143f, 0.71428573f, 1.f};
    float ov[8];
#pragma unroll
    for (int j = 0; j < 8; ++j) {
        const float z = (ild - PREFS[j]) * (1.0f / 0.3f);
        ov[j] = __expf(-0.5f * z * z);
    }
    float* oild = out + (size_t)NB * T * N_ITD + ((size_t)b * T + t) * N_ILD;
    *(float4*)(oild + 0) = make_float4(ov[0], ov[1], ov[2], ov[3]);
    *(float4*)(oild + 4) = make_float4(ov[4], ov[5], ov[6], ov[7]);
}

extern "C" void kernel_launch(void* const* d_in, const int* in_sizes, int n_in,
                              void* d_out, int out_size, void* d_ws, size_t ws_size,
                              hipStream_t stream) {
    const float* L = (const float*)d_in[0];
    const float* R = (const float*)d_in[1];
    float* out = (float*)d_out;
    dim3 grid(T / TILE, NB);   // 125 x 16 = 2000 blocks
    biaural_kernel<<<grid, dim3(TT), 0, stream>>>(L, R, out);
}

// Round 7
// 68.727 us; speedup vs baseline: 3.0789x; 1.8021x over previous
//
#include <hip/hip_runtime.h>

#define NB 16
#define T 16000
#define NF 64
#define TILE 64               // outputs per 1-wave block
#define WT 64                 // threads = 1 wave
#define HALO 32
#define ROWS (TILE + HALO)    // 96
#define RSU 18                // per-pass row stride in dwords: L dw 0..7, R dw 8..15, pad 2
#define NPASS 4               // 16 channels per pass
#define N_ITD 16
#define N_ILD 8

typedef _Float16 half2_t __attribute__((ext_vector_type(2)));

__device__ __forceinline__ unsigned int pk2h(float a, float b) {
    half2_t h;
    h.x = (_Float16)a;
    h.y = (_Float16)b;
    return __builtin_bit_cast(unsigned int, h);
}
__device__ __forceinline__ float dot2(unsigned int a, unsigned int b, float c) {
    return __builtin_amdgcn_fdot2(__builtin_bit_cast(half2_t, a),
                                  __builtin_bit_cast(half2_t, b), c, false);
}

// 1-wave blocks, NO barriers (wave-synchronous LDS). LDS = 96*18*4 = 6912 B
// -> ~16 independent waves/CU in decorrelated stage/compute phases.
// Staging loop is #pragma unroll 1: exact-trip unrolled staging spilled to
// scratch in rounds 4/5/6 (WRITE_SIZE 24->216 MB signature).
__global__ __launch_bounds__(WT, 4) void biaural_kernel(const float* __restrict__ L,
                                                        const float* __restrict__ R,
                                                        float* __restrict__ out) {
    __shared__ unsigned int sh[ROWS * RSU];

    const int b = blockIdx.y;
    const int t0 = blockIdx.x * TILE;
    const int tid = threadIdx.x;

    const float* __restrict__ Lb = L + (size_t)b * T * NF;
    const float* __restrict__ Rb = R + (size_t)b * T * NF;

    // staging decode (loop-invariant per lane): unit n = tid + 64j
    // sub = tid&3: 0 -> L chunk0, 1 -> L chunk1, 2 -> R chunk0, 3 -> R chunk1
    const int sub = tid & 3;
    const float* __restrict__ eb = (sub < 2) ? Lb : Rb;
    const int ch8 = (sub & 1) * 8;        // float offset within the pass's 16 ch
    const int r0 = tid >> 2;              // rows r0 + 16j, j = 0..5

    float acc[N_ITD];
#pragma unroll
    for (int i = 0; i < N_ITD; ++i) acc[i] = 0.f;
    float sumL = 0.f, sumR = 0.f;

    const int OFF[8] = {2, 6, 11, 15, 19, 23, 28, 32};
    const unsigned int ONE2 = 0x3C003C00u;   // (1.0h, 1.0h)
    const int cb = (HALO + tid) * RSU;

#pragma unroll 1
    for (int p = 0; p < NPASS; ++p) {
        const int pf = p * 16;            // channel offset of this pass

        // ---- stage [t0-32, t0+63] x 16ch of both ears as f16 (b128 writes).
        // unroll 1: keeps exactly one 32B load pair in flight per lane.
#pragma unroll 1
        for (int j = 0; j < 6; ++j) {
            const int row = r0 + 16 * j;
            const int gt = t0 - HALO + row;   // gt < T always (t0+63 <= 15999)
            uint4 pk = make_uint4(0u, 0u, 0u, 0u);
            if (gt >= 0) {
                const float* sp = eb + (size_t)gt * NF + pf + ch8;
                const float4 v0 = *(const float4*)sp;
                const float4 v1 = *(const float4*)(sp + 4);
                pk = make_uint4(pk2h(v0.x, v0.y), pk2h(v0.z, v0.w),
                                pk2h(v1.x, v1.y), pk2h(v1.z, v1.w));
            }
            *(uint4*)&sh[row * RSU + sub * 4] = pk;
        }
        // no __syncthreads: single wave, LDS ops in-order; compiler orders
        // the aliasing ds_write -> ds_read with lgkmcnt.

        // ---- compute this pass's 16 channels (2 chunks of 8)
#pragma unroll
        for (int c = 0; c < 2; ++c) {
            const uint4 lc = *(const uint4*)&sh[cb + c * 4];
            const uint4 rc = *(const uint4*)&sh[cb + 8 + c * 4];
            sumL = dot2(lc.x, ONE2, sumL); sumL = dot2(lc.y, ONE2, sumL);
            sumL = dot2(lc.z, ONE2, sumL); sumL = dot2(lc.w, ONE2, sumL);
            sumR = dot2(rc.x, ONE2, sumR); sumR = dot2(rc.y, ONE2, sumR);
            sumR = dot2(rc.z, ONE2, sumR); sumR = dot2(rc.w, ONE2, sumR);
#pragma unroll
            for (int k = 0; k < 8; ++k) {
                const int rb = cb - OFF[k] * RSU;
                const uint4 la = *(const uint4*)&sh[rb + c * 4];
                acc[8 + k] = dot2(la.x, rc.x, acc[8 + k]);
                acc[8 + k] = dot2(la.y, rc.y, acc[8 + k]);
                acc[8 + k] = dot2(la.z, rc.z, acc[8 + k]);
                acc[8 + k] = dot2(la.w, rc.w, acc[8 + k]);
                const uint4 ra = *(const uint4*)&sh[rb + 8 + c * 4];
                acc[7 - k] = dot2(lc.x, ra.x, acc[7 - k]);
                acc[7 - k] = dot2(lc.y, ra.y, acc[7 - k]);
                acc[7 - k] = dot2(lc.z, ra.z, acc[7 - k]);
                acc[7 - k] = dot2(lc.w, ra.w, acc[7 - k]);
            }
        }
    }

    const int t = t0 + tid;   // always < T (250*64 == 16000)
    // ---- ITD: [B,T,16]
    float* oitd = out + ((size_t)b * T + t) * N_ITD;
#pragma unroll
    for (int q = 0; q < 4; ++q) {
        *(float4*)(oitd + q * 4) =
            make_float4(acc[q * 4 + 0], acc[q * 4 + 1], acc[q * 4 + 2], acc[q * 4 + 3]);
    }

    // ---- ILD: [B,T,8] after the ITD block
    const float ild = (sumL - sumR) / (sumL + sumR + 1e-6f);
    const float PREFS[8] = {-1.f, -0.71428573f, -0.42857143f, -0.14285714f,
                            0.14285715f, 0.42857143f, 0.71428573f, 1.f};
    float ov[8];
#pragma unroll
    for (int j = 0; j < 8; ++j) {
        const float z = (ild - PREFS[j]) * (1.0f / 0.3f);
        ov[j] = __expf(-0.5f * z * z);
    }
    float* oild = out + (size_t)NB * T * N_ITD + ((size_t)b * T + t) * N_ILD;
    *(float4*)(oild + 0) = make_float4(ov[0], ov[1], ov[2], ov[3]);
    *(float4*)(oild + 4) = make_float4(ov[4], ov[5], ov[6], ov[7]);
}

extern "C" void kernel_launch(void* const* d_in, const int* in_sizes, int n_in,
                              void* d_out, int out_size, void* d_ws, size_t ws_size,
                              hipStream_t stream) {
    const float* L = (const float*)d_in[0];
    const float* R = (const float*)d_in[1];
    float* out = (float*)d_out;
    dim3 grid(T / TILE, NB);   // 250 x 16 = 4000 one-wave blocks
    biaural_kernel<<<grid, dim3(WT), 0, stream>>>(L, R, out);
}